// Round 3
// baseline (355.041 us; speedup 1.0000x reference)
//
#include <hip/hip_runtime.h>
#include <hip/hip_bf16.h>
#include <stdint.h>

#define B_  4
#define S_  2048
#define D_  1024
#define H_  16
#define HD_ 64
#define LOG2E 1.44269504088896f

typedef unsigned short u16;
typedef short bf16x8 __attribute__((ext_vector_type(8)));
typedef float f32x4 __attribute__((ext_vector_type(4)));

static __device__ __forceinline__ u16 f2bf(float f) {
    union { float f; uint32_t u; } v; v.f = f;
    return (u16)((v.u + 0x7FFF + ((v.u >> 16) & 1)) >> 16);
}

static __device__ __forceinline__ uint32_t cvt_pk_bf16(float lo, float hi) {
    uint32_t r;
    asm("v_cvt_pk_bf16_f32 %0, %1, %2" : "=v"(r) : "v"(lo), "v"(hi));
    return r;
}

// Swizzled 16B LDS read from a tile with 128B rows. slot = logical 16B column (0..7).
static __device__ __forceinline__ bf16x8 rd_swz(const u16* base, int row, int slot) {
    return *(const bf16x8*)((const char*)base + row * 128 + ((slot ^ (row & 7)) << 4));
}

// Swizzled 8B LDS read: lbyte = logical byte offset within the 128B row (8B aligned).
static __device__ __forceinline__ uint2 rd_swz8(const u16* base, int row, int lbyte) {
    return *(const uint2*)((const char*)base + row * 128 +
                           (((lbyte >> 4) ^ (row & 7)) << 4) + (lbyte & 15));
}

// global -> LDS direct copy (16B/lane) of one 8-row x 128B chunk; inverse swizzle
// on the GLOBAL side (linear LDS dest + pre-swizzled source + swizzled reads).
static __device__ __forceinline__ void gll_swz(const u16* grow0, size_t stride,
                                               u16* lds_chunk, int lane) {
    const int r = lane >> 3;
    const int slot = (lane & 7) ^ r;
    const u16* g = grow0 + (size_t)r * stride + slot * 8;
    __builtin_amdgcn_global_load_lds(
        (const __attribute__((address_space(1))) uint32_t*)g,
        (__attribute__((address_space(3))) uint32_t*)lds_chunk, 16, 0, 0);
}

// ---------------- weight transpose + bf16 convert: Wt[n][k] = bf16(W[k][n]) ----------------
__global__ __launch_bounds__(256) void wtrans(
    const float* __restrict__ W0, const float* __restrict__ W1, const float* __restrict__ W2,
    u16* __restrict__ T0, u16* __restrict__ T1, u16* __restrict__ T2)
{
    const float* W = blockIdx.z == 0 ? W0 : (blockIdx.z == 1 ? W1 : W2);
    u16* T       = blockIdx.z == 0 ? T0 : (blockIdx.z == 1 ? T1 : T2);
    __shared__ float t[32][33];
    const int n0 = blockIdx.x * 32, k0 = blockIdx.y * 32;
    const int tx = threadIdx.x, ty = threadIdx.y;
#pragma unroll
    for (int i = 0; i < 4; ++i)
        t[ty + i * 8][tx] = W[(size_t)(k0 + ty + i * 8) * D_ + n0 + tx];
    __syncthreads();
#pragma unroll
    for (int i = 0; i < 4; ++i)
        T[(size_t)(n0 + ty + i * 8) * D_ + k0 + tx] = f2bf(t[tx][ty + i * 8]);
}

// ---------------- projection GEMM: Y = X @ Wt^T + b ----------------
// MODE 0: Q -> (B,H,S,HD) bf16, scaled by 0.125*log2(e)  (softmax in base-2 domain)
// MODE 1: K -> (B,H,S,HD) bf16
// MODE 2: V -> (B,H,HD,S) bf16 (transposed for NT-form PV)
template <int MODE>
__global__ __launch_bounds__(256) void proj_gemm(
    const float* __restrict__ X, const u16* __restrict__ Wt,
    const float* __restrict__ bias, u16* __restrict__ out)
{
    __shared__ __align__(16) u16 lA[128 * 64];
    __shared__ __align__(16) u16 lB[128 * 64];
    const int tid = threadIdx.x;
    // XCD-aware mapping: all 8 n-tiles of one m-panel land on one XCD consecutively.
    const int bx = blockIdx.x;
    const int mt = (bx & 7) + ((bx >> 6) << 3);  // 0..63
    const int nt = (bx >> 3) & 7;                // 0..7
    const int m0 = mt * 128, n0 = nt * 128;
    const int w = tid >> 6, lane = tid & 63;
    const int lr = lane & 15, lg = lane >> 4;
    const int wr = (w >> 1) * 64, wc = (w & 1) * 64;

    f32x4 acc[4][4] = {};

    for (int k0 = 0; k0 < D_; k0 += 64) {
        __syncthreads();
#pragma unroll
        for (int i = 0; i < 4; ++i) {
            const int c = w * 4 + i;
            gll_swz(Wt + (size_t)(n0 + c * 8) * D_ + k0, D_, &lB[c * 512], lane);
        }
#pragma unroll
        for (int i = 0; i < 8; ++i) {
            const int lin = i * 1024 + tid * 4;
            const int r = lin >> 6, c = lin & 63;
            const float4 v = *(const float4*)(X + (size_t)(m0 + r) * D_ + k0 + c);
            uint2 pk;
            pk.x = cvt_pk_bf16(v.x, v.y);
            pk.y = cvt_pk_bf16(v.z, v.w);
            const int phys = r * 128 + (((c >> 3) ^ (r & 7)) << 4) + ((c & 7) << 1);
            *(uint2*)((char*)lA + phys) = pk;
        }
        __syncthreads();
#pragma unroll
        for (int kk = 0; kk < 64; kk += 32) {
            bf16x8 af[4], bfr[4];
#pragma unroll
            for (int m = 0; m < 4; ++m)
                af[m] = rd_swz(lA, wr + m * 16 + lr, (kk >> 3) + lg);
#pragma unroll
            for (int n = 0; n < 4; ++n)
                bfr[n] = rd_swz(lB, wc + n * 16 + lr, (kk >> 3) + lg);
#pragma unroll
            for (int m = 0; m < 4; ++m)
#pragma unroll
                for (int n = 0; n < 4; ++n)
                    acc[m][n] = __builtin_amdgcn_mfma_f32_16x16x32_bf16(af[m], bfr[n], acc[m][n], 0, 0, 0);
        }
    }
#pragma unroll
    for (int m = 0; m < 4; ++m)
#pragma unroll
        for (int n = 0; n < 4; ++n)
#pragma unroll
            for (int j = 0; j < 4; ++j) {
                const int gm = m0 + wr + m * 16 + lg * 4 + j;
                const int gn = n0 + wc + n * 16 + lr;
                float y = acc[m][n][j] + bias[gn];
                if (MODE == 0) y *= 0.125f * LOG2E;
                const int bb = gm >> 11, s = gm & (S_ - 1);
                const int h = gn >> 6, hd = gn & 63;
                size_t off;
                if (MODE < 2) off = (((size_t)bb * H_ + h) * S_ + s) * HD_ + hd;
                else          off = (((size_t)bb * H_ + h) * HD_ + hd) * S_ + s;
                out[off] = f2bf(y);
            }
}

// ---------------- causal flash attention, swapped-QK^T in-register softmax ----------------
// grid: (32, B*H), block 256 (4 waves x 16 q-rows = 64-row q-tile).
// LPT: qi = 31 - bx so the longest blocks dispatch first.
// Swapped QK^T: sacc[n][j] = S^T[kv = 16n + 4lg + j][q = lr]  -> lane owns q-row lr.
// PV kv-permutation pi(m,lg,jj) = 32m + 16(jj>>2) + 4lg + (jj&3): A-frag = lane's own
// cvt_pk words (no cross-lane), V-frag = two ds_read_b64 honoring the same pi.
__global__ __launch_bounds__(256, 8) void attn_kernel(
    const u16* __restrict__ qb, const u16* __restrict__ kb,
    const u16* __restrict__ vtb, float* __restrict__ out)
{
    const int bh = blockIdx.y;
    const int b = bh >> 4, h = bh & 15;
    const int qi = 31 - (int)blockIdx.x;
    const int q0 = qi * 64;
    const int tid = threadIdx.x;
    const int w = tid >> 6, lane = tid & 63;
    const int lr = lane & 15, lg = lane >> 4;

    __shared__ __align__(16) u16 lK[64 * 64];  // [kv][d], swizzled
    __shared__ __align__(16) u16 lV[64 * 64];  // [d][kv], swizzled

    const size_t kbase = (size_t)bh * S_ * HD_;
    const size_t vbase = (size_t)bh * HD_ * S_;

    const int qrow = q0 + w * 16 + lr;
    const size_t qoff = ((size_t)bh * S_ + qrow) * HD_;
    const bf16x8 qf0 = *(const bf16x8*)(qb + qoff + lg * 8);
    const bf16x8 qf1 = *(const bf16x8*)(qb + qoff + 32 + lg * 8);

    f32x4 oacc[4] = {};
    float m_run = -1e30f, l_run = 0.f;

    for (int t = 0; t <= qi; ++t) {
        const int kv0 = t * 64;
        __syncthreads();
        gll_swz(kb + kbase + (size_t)(kv0 + w * 8) * HD_, HD_, &lK[w * 512], lane);
        gll_swz(kb + kbase + (size_t)(kv0 + (w + 4) * 8) * HD_, HD_, &lK[(w + 4) * 512], lane);
        gll_swz(vtb + vbase + (size_t)(w * 8) * S_ + kv0, S_, &lV[w * 512], lane);
        gll_swz(vtb + vbase + (size_t)((w + 4) * 8) * S_ + kv0, S_, &lV[(w + 4) * 512], lane);
        __syncthreads();

        // S^T = K Q^T (swapped operands)
        f32x4 sacc[4];
        __builtin_amdgcn_s_setprio(1);
#pragma unroll
        for (int n = 0; n < 4; ++n) {
            const bf16x8 k0f = rd_swz(lK, n * 16 + lr, lg);
            const bf16x8 k1f = rd_swz(lK, n * 16 + lr, 4 + lg);
            f32x4 z = {};
            z = __builtin_amdgcn_mfma_f32_16x16x32_bf16(k0f, qf0, z, 0, 0, 0);
            z = __builtin_amdgcn_mfma_f32_16x16x32_bf16(k1f, qf1, z, 0, 0, 0);
            sacc[n] = z;
        }
        __builtin_amdgcn_s_setprio(0);

        // causal mask on diagonal tile: kv_rel > q_rel
        if (t == qi) {
            const int q_rel = w * 16 + lr;
#pragma unroll
            for (int n = 0; n < 4; ++n)
#pragma unroll
                for (int j = 0; j < 4; ++j)
                    if (n * 16 + lg * 4 + j > q_rel) sacc[n][j] = -1e30f;
        }

        // in-register softmax for q-row lr (base-2 domain; log2e folded into Q)
        float rm = -1e30f;
#pragma unroll
        for (int n = 0; n < 4; ++n)
#pragma unroll
            for (int j = 0; j < 4; ++j) rm = fmaxf(rm, sacc[n][j]);
        rm = fmaxf(rm, __shfl_xor(rm, 16));
        rm = fmaxf(rm, __shfl_xor(rm, 32));
        const float mn = fmaxf(m_run, rm);
        const float alpha = exp2f(m_run - mn);
        m_run = mn;
        float rs = 0.f;
#pragma unroll
        for (int n = 0; n < 4; ++n)
#pragma unroll
            for (int j = 0; j < 4; ++j) {
                const float p = exp2f(sacc[n][j] - mn);
                sacc[n][j] = p;
                rs += p;
            }
        rs += __shfl_xor(rs, 16);
        rs += __shfl_xor(rs, 32);
        l_run = l_run * alpha + rs;

        // pack P to bf16 words: pw[n][jh] = (p[n][2jh], p[n][2jh+1])
        uint32_t pw[4][2];
#pragma unroll
        for (int n = 0; n < 4; ++n)
#pragma unroll
            for (int jh = 0; jh < 2; ++jh)
                pw[n][jh] = cvt_pk_bf16(sacc[n][2 * jh], sacc[n][2 * jh + 1]);

        // rescale O by alpha of each output q-row (rows lg*4+j live on lanes lr=lg*4+j)
#pragma unroll
        for (int j = 0; j < 4; ++j) {
            const float a = __shfl(alpha, lg * 4 + j);
#pragma unroll
            for (int n = 0; n < 4; ++n) oacc[n][j] *= a;
        }

        // PV: O[q][d] += P V, honoring pi on both operands
        __builtin_amdgcn_s_setprio(1);
#pragma unroll
        for (int n = 0; n < 4; ++n) {
            const int row = n * 16 + lr;
#pragma unroll
            for (int m = 0; m < 2; ++m) {
                const uint2 lo = rd_swz8(lV, row, 64 * m + 8 * lg);
                const uint2 hi = rd_swz8(lV, row, 64 * m + 8 * lg + 32);
                union { uint32_t u[4]; bf16x8 v; } vf, af;
                vf.u[0] = lo.x; vf.u[1] = lo.y; vf.u[2] = hi.x; vf.u[3] = hi.y;
                af.u[0] = pw[2 * m][0]; af.u[1] = pw[2 * m][1];
                af.u[2] = pw[2 * m + 1][0]; af.u[3] = pw[2 * m + 1][1];
                oacc[n] = __builtin_amdgcn_mfma_f32_16x16x32_bf16(af.v, vf.v, oacc[n], 0, 0, 0);
            }
        }
        __builtin_amdgcn_s_setprio(0);
    }

    // epilogue
    const float inv = 1.f / l_run;
#pragma unroll
    for (int j = 0; j < 4; ++j) {
        const float iv = __shfl(inv, lg * 4 + j);
        const int row = q0 + w * 16 + lg * 4 + j;
#pragma unroll
        for (int n = 0; n < 4; ++n)
            out[((size_t)b * S_ + row) * D_ + h * HD_ + n * 16 + lr] = oacc[n][j] * iv;
    }
}

extern "C" void kernel_launch(void* const* d_in, const int* in_sizes, int n_in,
                              void* d_out, int out_size, void* d_ws, size_t ws_size,
                              hipStream_t stream) {
    const float* Q  = (const float*)d_in[0];
    const float* K  = (const float*)d_in[1];
    const float* V  = (const float*)d_in[2];
    const float* Wq = (const float*)d_in[3];
    const float* bq = (const float*)d_in[4];
    const float* Wk = (const float*)d_in[5];
    const float* bk = (const float*)d_in[6];
    const float* Wv = (const float*)d_in[7];
    const float* bv = (const float*)d_in[8];
    float* out = (float*)d_out;

    char* ws = (char*)d_ws;
    const size_t WT_BYTES  = (size_t)D_ * D_ * 2;
    const size_t QKV_BYTES = (size_t)B_ * S_ * D_ * 2;
    u16* Wtq = (u16*)(ws);
    u16* Wtk = (u16*)(ws + WT_BYTES);
    u16* Wtv = (u16*)(ws + 2 * WT_BYTES);
    u16* qb  = (u16*)(ws + 3 * WT_BYTES);
    u16* kb  = (u16*)(ws + 3 * WT_BYTES + QKV_BYTES);
    u16* vtb = (u16*)(ws + 3 * WT_BYTES + 2 * QKV_BYTES);

    wtrans<<<dim3(32, 32, 3), dim3(32, 8), 0, stream>>>(Wq, Wk, Wv, Wtq, Wtk, Wtv);
    proj_gemm<0><<<dim3(512), dim3(256), 0, stream>>>(Q, Wtq, bq, qb);
    proj_gemm<1><<<dim3(512), dim3(256), 0, stream>>>(K, Wtk, bk, kb);
    proj_gemm<2><<<dim3(512), dim3(256), 0, stream>>>(V, Wtv, bv, vtb);
    attn_kernel<<<dim3(32, B_ * H_), dim3(256), 0, stream>>>(qb, kb, vtb, out);
}

// Round 4
// 179.922 us; speedup vs baseline: 1.9733x; 1.9733x over previous
//
#include <hip/hip_runtime.h>
#include <hip/hip_bf16.h>
#include <stdint.h>

#define B_  4
#define S_  2048
#define D_  1024
#define H_  16
#define HD_ 64
#define LOG2E 1.44269504088896f

typedef unsigned short u16;
typedef short bf16x8 __attribute__((ext_vector_type(8)));
typedef float f32x4 __attribute__((ext_vector_type(4)));

static __device__ __forceinline__ u16 f2bf(float f) {
    union { float f; uint32_t u; } v; v.f = f;
    return (u16)((v.u + 0x7FFF + ((v.u >> 16) & 1)) >> 16);
}

static __device__ __forceinline__ uint32_t cvt_pk_bf16(float lo, float hi) {
    uint32_t r;
    asm("v_cvt_pk_bf16_f32 %0, %1, %2" : "=v"(r) : "v"(lo), "v"(hi));
    return r;
}

// Swizzled 16B LDS read from a tile with 128B rows. slot = logical 16B column (0..7).
static __device__ __forceinline__ bf16x8 rd_swz(const u16* base, int row, int slot) {
    return *(const bf16x8*)((const char*)base + row * 128 + ((slot ^ (row & 7)) << 4));
}

// global -> LDS direct copy (16B/lane) of one 8-row x 128B chunk; inverse swizzle
// on the GLOBAL side (linear LDS dest + pre-swizzled source + swizzled reads).
static __device__ __forceinline__ void gll_swz(const u16* grow0, size_t stride,
                                               u16* lds_chunk, int lane) {
    const int r = lane >> 3;
    const int slot = (lane & 7) ^ r;
    const u16* g = grow0 + (size_t)r * stride + slot * 8;
    __builtin_amdgcn_global_load_lds(
        (const __attribute__((address_space(1))) uint32_t*)g,
        (__attribute__((address_space(3))) uint32_t*)lds_chunk, 16, 0, 0);
}

// ---------------- weight transpose + bf16 convert: Wt[n][k] = bf16(W[k][n]) ----------------
__global__ __launch_bounds__(256) void wtrans(
    const float* __restrict__ W0, const float* __restrict__ W1, const float* __restrict__ W2,
    u16* __restrict__ T0, u16* __restrict__ T1, u16* __restrict__ T2)
{
    const float* W = blockIdx.z == 0 ? W0 : (blockIdx.z == 1 ? W1 : W2);
    u16* T       = blockIdx.z == 0 ? T0 : (blockIdx.z == 1 ? T1 : T2);
    __shared__ float t[32][33];
    const int n0 = blockIdx.x * 32, k0 = blockIdx.y * 32;
    const int tx = threadIdx.x, ty = threadIdx.y;
#pragma unroll
    for (int i = 0; i < 4; ++i)
        t[ty + i * 8][tx] = W[(size_t)(k0 + ty + i * 8) * D_ + n0 + tx];
    __syncthreads();
#pragma unroll
    for (int i = 0; i < 4; ++i)
        T[(size_t)(n0 + ty + i * 8) * D_ + k0 + tx] = f2bf(t[tx][ty + i * 8]);
}

// ---------------- projection GEMM: Y = X @ Wt^T + b ----------------
// MODE 0: Q -> (B,H,S,HD) bf16, scaled by 0.125*log2(e)  (softmax in base-2 domain)
// MODE 1: K -> (B,H,S,HD) bf16
// MODE 2: V -> (B,H,HD,S) bf16, kv permuted within each 64-block (rho) for b128 PV reads
template <int MODE>
__global__ __launch_bounds__(256) void proj_gemm(
    const float* __restrict__ X, const u16* __restrict__ Wt,
    const float* __restrict__ bias, u16* __restrict__ out)
{
    __shared__ __align__(16) u16 lA[128 * 64];
    __shared__ __align__(16) u16 lB[128 * 64];
    const int tid = threadIdx.x;
    const int m0 = blockIdx.x * 128, n0 = blockIdx.y * 128;
    const int w = tid >> 6, lane = tid & 63;
    const int lr = lane & 15, lg = lane >> 4;
    const int wr = (w >> 1) * 64, wc = (w & 1) * 64;

    f32x4 acc[4][4] = {};

    for (int k0 = 0; k0 < D_; k0 += 64) {
        __syncthreads();
#pragma unroll
        for (int i = 0; i < 4; ++i) {
            const int c = w * 4 + i;
            gll_swz(Wt + (size_t)(n0 + c * 8) * D_ + k0, D_, &lB[c * 512], lane);
        }
#pragma unroll
        for (int i = 0; i < 8; ++i) {
            const int lin = i * 1024 + tid * 4;
            const int r = lin >> 6, c = lin & 63;
            const float4 v = *(const float4*)(X + (size_t)(m0 + r) * D_ + k0 + c);
            uint2 pk;
            pk.x = (uint32_t)f2bf(v.x) | ((uint32_t)f2bf(v.y) << 16);
            pk.y = (uint32_t)f2bf(v.z) | ((uint32_t)f2bf(v.w) << 16);
            const int phys = r * 128 + (((c >> 3) ^ (r & 7)) << 4) + ((c & 7) << 1);
            *(uint2*)((char*)lA + phys) = pk;
        }
        __syncthreads();
#pragma unroll
        for (int kk = 0; kk < 64; kk += 32) {
            bf16x8 af[4], bfr[4];
#pragma unroll
            for (int m = 0; m < 4; ++m)
                af[m] = rd_swz(lA, wr + m * 16 + lr, (kk >> 3) + lg);
#pragma unroll
            for (int n = 0; n < 4; ++n)
                bfr[n] = rd_swz(lB, wc + n * 16 + lr, (kk >> 3) + lg);
#pragma unroll
            for (int m = 0; m < 4; ++m)
#pragma unroll
                for (int n = 0; n < 4; ++n)
                    acc[m][n] = __builtin_amdgcn_mfma_f32_16x16x32_bf16(af[m], bfr[n], acc[m][n], 0, 0, 0);
        }
    }
#pragma unroll
    for (int m = 0; m < 4; ++m)
#pragma unroll
        for (int n = 0; n < 4; ++n)
#pragma unroll
            for (int j = 0; j < 4; ++j) {
                const int gm = m0 + wr + m * 16 + lg * 4 + j;
                const int gn = n0 + wc + n * 16 + lr;
                float y = acc[m][n][j] + bias[gn];
                if (MODE == 0) y *= 0.125f * LOG2E;
                const int bb = gm >> 11, s = gm & (S_ - 1);
                const int h = gn >> 6, hd = gn & 63;
                size_t off;
                if (MODE < 2) off = (((size_t)bb * H_ + h) * S_ + s) * HD_ + hd;
                else {
                    // rho: position p holds kv = 32m+16(jj>>2)+4lg+(jj&3); store kv s at p
                    const int s6 = s & 63;
                    const int sp = (s & ~63) | (s6 & 0x20) | ((s6 & 0xC) << 1) |
                                   ((s6 & 0x10) >> 2) | (s6 & 3);
                    off = (((size_t)bb * H_ + h) * HD_ + hd) * S_ + sp;
                }
                out[off] = f2bf(y);
            }
}

// ---------------- causal flash attention, swapped-QK^T in-register softmax ----------------
// grid: (8, B*H), block 512 (8 waves x 16 q-rows = 128-row q-tile).
// Block bx processes q-tile pair (bx, 15-bx): uniform 34 KV-tiles per block.
// Swapped QK^T: sacc[n][j] = S^T[kv_rel = 16n+4lg+j][q = lr] -> softmax needs only
// xor16/xor32 shfls. PV A-frag = lane's own cvt_pk words (kv-permutation pi matches
// the rho-permuted V layout), B-frag = one swizzled ds_read_b128.
__global__ __launch_bounds__(512) void attn_kernel(
    const u16* __restrict__ qb, const u16* __restrict__ kb,
    const u16* __restrict__ vtb, float* __restrict__ out)
{
    const int bh = blockIdx.y;
    const int b = bh >> 4, h = bh & 15;
    const int tid = threadIdx.x;
    const int w = tid >> 6, lane = tid & 63;
    const int lr = lane & 15, lg = lane >> 4;

    __shared__ __align__(16) u16 lK[64 * 64];  // [kv][d], swizzled
    __shared__ __align__(16) u16 lV[64 * 64];  // [d][kv-rho], swizzled

    const size_t kbase = (size_t)bh * S_ * HD_;
    const size_t vbase = (size_t)bh * HD_ * S_;

    for (int e = 0; e < 2; ++e) {
        const int qi = (e == 0) ? (int)blockIdx.x : 15 - (int)blockIdx.x;
        const int q0 = qi * 128;
        const int qrow = q0 + w * 16 + lr;

        const size_t qoff = ((size_t)bh * S_ + qrow) * HD_;
        const bf16x8 qf0 = *(const bf16x8*)(qb + qoff + lg * 8);
        const bf16x8 qf1 = *(const bf16x8*)(qb + qoff + 32 + lg * 8);

        f32x4 oacc[4] = {};
        float m_run = -1e30f, l_run = 0.f;

        const int tmax = 2 * qi + 1;
        for (int t = 0; t <= tmax; ++t) {
            const int kv0 = t * 64;
            __syncthreads();  // prior tile's LDS reads done
            gll_swz(kb + kbase + (size_t)(kv0 + w * 8) * HD_, HD_, &lK[w * 512], lane);
            gll_swz(vtb + vbase + (size_t)(w * 8) * S_ + kv0, S_, &lV[w * 512], lane);
            __syncthreads();  // vmcnt drained by compiler before barrier

            // last tile of this q-tile: waves 0-3 are fully above the diagonal
            if (t == tmax && w < 4) continue;  // no barriers below in this iteration

            // S^T = K Q^T (swapped operands)
            f32x4 sacc[4];
            __builtin_amdgcn_s_setprio(1);
#pragma unroll
            for (int n = 0; n < 4; ++n) {
                const bf16x8 k0f = rd_swz(lK, n * 16 + lr, lg);
                const bf16x8 k1f = rd_swz(lK, n * 16 + lr, 4 + lg);
                f32x4 z = {};
                z = __builtin_amdgcn_mfma_f32_16x16x32_bf16(k0f, qf0, z, 0, 0, 0);
                z = __builtin_amdgcn_mfma_f32_16x16x32_bf16(k1f, qf1, z, 0, 0, 0);
                sacc[n] = z;
            }
            __builtin_amdgcn_s_setprio(0);

            // causal mask (only the last two tiles can straddle the diagonal)
            if (t >= tmax - 1) {
#pragma unroll
                for (int n = 0; n < 4; ++n)
#pragma unroll
                    for (int j = 0; j < 4; ++j)
                        if (kv0 + n * 16 + lg * 4 + j > qrow) sacc[n][j] = -1e30f;
            }

            // in-register softmax for q-row lr (base-2; log2e folded into Q scale)
            float rm = -1e30f;
#pragma unroll
            for (int n = 0; n < 4; ++n)
#pragma unroll
                for (int j = 0; j < 4; ++j) rm = fmaxf(rm, sacc[n][j]);
            rm = fmaxf(rm, __shfl_xor(rm, 16));
            rm = fmaxf(rm, __shfl_xor(rm, 32));
            const float mn = fmaxf(m_run, rm);
            const float alpha = exp2f(m_run - mn);
            m_run = mn;
            float rs = 0.f;
#pragma unroll
            for (int n = 0; n < 4; ++n)
#pragma unroll
                for (int j = 0; j < 4; ++j) {
                    const float p = exp2f(sacc[n][j] - mn);
                    sacc[n][j] = p;
                    rs += p;
                }
            rs += __shfl_xor(rs, 16);
            rs += __shfl_xor(rs, 32);
            l_run = l_run * alpha + rs;

            // pack P to bf16 words: pw[n][jh] = (p at kv 16n+4lg+2jh, +1)
            uint32_t pw[4][2];
#pragma unroll
            for (int n = 0; n < 4; ++n)
#pragma unroll
                for (int jh = 0; jh < 2; ++jh)
                    pw[n][jh] = cvt_pk_bf16(sacc[n][2 * jh], sacc[n][2 * jh + 1]);

            // rescale O (row lg*4+j's alpha lives on lane lr==lg*4+j, any lg copy)
#pragma unroll
            for (int j = 0; j < 4; ++j) {
                const float a = __shfl(alpha, lg * 4 + j);
#pragma unroll
                for (int n = 0; n < 4; ++n) oacc[n][j] *= a;
            }

            // PV: O[q][d] += P V; V rho-layout makes B-frag one b128 at slot 4m+lg
            __builtin_amdgcn_s_setprio(1);
#pragma unroll
            for (int n = 0; n < 4; ++n) {
                const int row = n * 16 + lr;
#pragma unroll
                for (int m = 0; m < 2; ++m) {
                    const bf16x8 vf = rd_swz(lV, row, 4 * m + lg);
                    union { uint32_t u[4]; bf16x8 v; } af;
                    af.u[0] = pw[2 * m][0]; af.u[1] = pw[2 * m][1];
                    af.u[2] = pw[2 * m + 1][0]; af.u[3] = pw[2 * m + 1][1];
                    oacc[n] = __builtin_amdgcn_mfma_f32_16x16x32_bf16(af.v, vf, oacc[n], 0, 0, 0);
                }
            }
            __builtin_amdgcn_s_setprio(0);
        }

        // epilogue for this q-tile
        const float inv = 1.f / l_run;
#pragma unroll
        for (int j = 0; j < 4; ++j) {
            const float iv = __shfl(inv, lg * 4 + j);
            const int row = q0 + w * 16 + lg * 4 + j;
#pragma unroll
            for (int n = 0; n < 4; ++n)
                out[((size_t)b * S_ + row) * D_ + h * HD_ + n * 16 + lr] = oacc[n][j] * iv;
        }
    }
}

extern "C" void kernel_launch(void* const* d_in, const int* in_sizes, int n_in,
                              void* d_out, int out_size, void* d_ws, size_t ws_size,
                              hipStream_t stream) {
    const float* Q  = (const float*)d_in[0];
    const float* K  = (const float*)d_in[1];
    const float* V  = (const float*)d_in[2];
    const float* Wq = (const float*)d_in[3];
    const float* bq = (const float*)d_in[4];
    const float* Wk = (const float*)d_in[5];
    const float* bk = (const float*)d_in[6];
    const float* Wv = (const float*)d_in[7];
    const float* bv = (const float*)d_in[8];
    float* out = (float*)d_out;

    char* ws = (char*)d_ws;
    const size_t WT_BYTES  = (size_t)D_ * D_ * 2;
    const size_t QKV_BYTES = (size_t)B_ * S_ * D_ * 2;
    u16* Wtq = (u16*)(ws);
    u16* Wtk = (u16*)(ws + WT_BYTES);
    u16* Wtv = (u16*)(ws + 2 * WT_BYTES);
    u16* qb  = (u16*)(ws + 3 * WT_BYTES);
    u16* kb  = (u16*)(ws + 3 * WT_BYTES + QKV_BYTES);
    u16* vtb = (u16*)(ws + 3 * WT_BYTES + 2 * QKV_BYTES);

    wtrans<<<dim3(32, 32, 3), dim3(32, 8), 0, stream>>>(Wq, Wk, Wv, Wtq, Wtk, Wtv);
    proj_gemm<0><<<dim3(64, 8), dim3(256), 0, stream>>>(Q, Wtq, bq, qb);
    proj_gemm<1><<<dim3(64, 8), dim3(256), 0, stream>>>(K, Wtk, bk, kb);
    proj_gemm<2><<<dim3(64, 8), dim3(256), 0, stream>>>(V, Wtv, bv, vtb);
    attn_kernel<<<dim3(8, B_ * H_), dim3(512), 0, stream>>>(qb, kb, vtb, out);
}